// Round 17
// baseline (37.288 us; speedup 1.0000x reference)
//
#include <hip/hip_runtime.h>

// Barnes-Wall Lambda16 quantizer — 2 rows per thread (ILP version).
//
// R11-R16 plateau analysis: t ~ 11us fixed + 5.9ns/instr until ~R11, then
// flat — at grid-capped 4 waves/SIMD, ~50% of real time all waves stall on
// dependencies simultaneously. This round: each thread processes TWO
// independent rows (t and t+N/2), fully interleaved. Total work unchanged
// (no duplication — R9/R13's failure mode), waves halve to 2/SIMD, but each
// wave now has 2 independent chains filling its own stall slots.
// Register budget: pass-1 peak ~156 live < (256,1) target ~200 (R3).
//
// All math is R16-verbatim (validated absmax 0.0 through R16):
//   pass-1: WHT ssum + butterfly max-DP + PAR32, fully unrolled, zero
//   memory ops; stable top-3 per row (strict <, earlier k wins ties).
//   pass-2: zero-LDS eval_k (popcount codebook), 3 merged-emit evals,
//   lexicographic (D,k) == numpy first-min, epilogue scaling.
//
// Pass-2 bit-exactness invariants (absmax must be 0.0):
//  - fp contract OFF; fmaf only where exact or single-rounding-identical:
//    fmaf(c,-0.5,xh) == fl(xh-c/2); fmaf(2,f,c) exact; Xp=fmaf(bit,+-2,X)
//    exact; e = fmaf(-2,xh,Xp) == fl(Xp-x) single rounding (x=2*xh exact).
//  - rintf == round-half-to-even == np.round; dd = x2 - f exact.
//  - first-max: contiguous-pair tournament, left wins ties (>=).
//  - parity (pass-2): float sum-tree of integer-valued f (exact), cvt, &1.
//  - D in numpy's n=16 pairwise order:
//    r[j]=sq[j]+sq[j+8]; D=((r0+r1)+(r2+r3))+((r4+r5)+(r6+r7)).
//
// Gates: VGPR 150-200, FETCH ~8.3 MB, WRITE ~16.4 MB (no scratch).
// If neutral (>=23.4us): the plateau is a structural floor -> restore R15.

constexpr int G5[5][16] = {
    {1,1,1,1,0,1,0,1,1,0,0,1,0,0,0,0},
    {0,1,1,1,1,0,1,0,1,1,0,0,1,0,0,0},
    {0,0,1,1,1,1,0,1,0,1,1,0,0,1,0,0},
    {0,0,0,1,1,1,1,0,1,0,1,1,0,0,1,0},
    {1,1,1,1,1,1,1,1,1,1,1,1,1,1,1,1}};

struct Tabs {
  int m[16];        // column bit-masks: c_j(k) = popcount(k & m[j])
  int pt[16];       // pt[j] = 4-bit point (rows 0..3 at column j), bijective
  unsigned rowm[5]; // Row_i as bitmask over j
  unsigned par2w;   // bit k = par2(k) = XOR_j (c_j(k)>>1)&1
};
constexpr Tabs make_tabs() {
  Tabs t{};
  for (int j = 0; j < 16; ++j) {
    int m = 0;
    for (int i = 0; i < 5; ++i) m |= G5[i][j] << (4 - i);
    t.m[j] = m;
    t.pt[j] = (G5[0][j] << 3) | (G5[1][j] << 2) | (G5[2][j] << 1) | G5[3][j];
  }
  for (int i = 0; i < 5; ++i) {
    unsigned rm = 0;
    for (int j = 0; j < 16; ++j) rm |= (unsigned)G5[i][j] << j;
    t.rowm[i] = rm;
  }
  t.par2w = 0;
  for (int k = 0; k < 32; ++k) {
    unsigned p2 = 0;
    for (int j = 0; j < 16; ++j) {
      int c = 0;
      for (int i = 0; i < 5; ++i) c += ((k >> (4 - i)) & 1) * G5[i][j];
      p2 ^= (unsigned)((c >> 1) & 1);
    }
    t.par2w |= p2 << k;
  }
  return t;
}
constexpr Tabs tb = make_tabs();

__device__ __forceinline__ int parity16i(const float (&f)[16]) {
  // exact: all addends are small integers
  float s0 = ((f[0] + f[1]) + (f[2] + f[3])) + ((f[4] + f[5]) + (f[6] + f[7]));
  float s1 = ((f[8] + f[9]) + (f[10] + f[11])) + ((f[12] + f[13]) + (f[14] + f[15]));
  return ((int)(s0 + s1)) & 1;
}

// Exact numpy-pipeline evaluation of candidate kk (R2..R16-verified).
// Codeword via popcount (no LDS). Emits UNSCALED Xp into y.
__device__ __forceinline__ float eval_k(int kk, const float (&xh)[16],
                                        float (&y)[16]) {
#pragma clang fp contract(off)
  float cf[16], f[16], dd[16];
#pragma unroll
  for (int j = 0; j < 16; ++j) {
    cf[j] = (float)__builtin_popcount(kk & tb.m[j]);
    float x2 = __builtin_fmaf(cf[j], -0.5f, xh[j]);  // == fl(xh - c/2)
    float fj = __builtin_rintf(x2);
    f[j] = fj;
    dd[j] = x2 - fj;                                 // exact
  }
  const int par = parity16i(f);

  // first-occurrence argmax of |dd| -> onehot (left wins ties)
  float tv[16];
  int ti[16];
#pragma unroll
  for (int j = 0; j < 16; ++j) { tv[j] = __builtin_fabsf(dd[j]); ti[j] = 1 << j; }
#pragma unroll
  for (int w = 8; w >= 1; w >>= 1) {
#pragma unroll
    for (int j = 0; j < w; ++j) {
      bool L = tv[2 * j] >= tv[2 * j + 1];
      tv[j] = L ? tv[2 * j] : tv[2 * j + 1];
      ti[j] = L ? ti[2 * j] : ti[2 * j + 1];
    }
  }
  const int ohm = par ? ti[0] : 0;   // patch mask (0 when parity even)

  float sq[16];
#pragma unroll
  for (int j = 0; j < 16; ++j) {
    float X  = __builtin_fmaf(2.0f, f[j], cf[j]);      // exact int
    float s2 = __builtin_copysignf(2.0f, dd[j]);       // corr direction
    float bitf = (float)((ohm >> j) & 1);
    float Xp = __builtin_fmaf(bitf, s2, X);            // exact int
    float e  = __builtin_fmaf(-2.0f, xh[j], Xp);       // == fl(Xp - x)
    sq[j] = e * e;
    y[j] = Xp;                                         // unscaled
  }
  float r0 = sq[0] + sq[8],  r1 = sq[1] + sq[9];
  float r2 = sq[2] + sq[10], r3 = sq[3] + sq[11];
  float r4 = sq[4] + sq[12], r5 = sq[5] + sq[13];
  float r6 = sq[6] + sq[14], r7 = sq[7] + sq[15];
  return ((r0 + r1) + (r2 + r3)) + ((r4 + r5) + (r6 + r7));
}

__global__ __launch_bounds__(256, 1) void bw_quant_kernel(
    const float* __restrict__ x_in,
    const float* __restrict__ C_rep,   // unused (constexpr codebook)
    const float* __restrict__ a_ptr,
    float* __restrict__ y_out,
    int n_rows)
{
#pragma clang fp contract(off)
  const int halfN = n_rows >> 1;
  const int t0 = blockIdx.x * 256 + threadIdx.x;
  if (t0 >= halfN) return;
  const int rows[2] = {t0, t0 + halfN};

  const float a = a_ptr[0];

  // -------- prologue per row: xh, residuals, WHT->h, maxDP->T/S, PAR ------
  float xh[2][16], h[2][16], T[2][16], S[2][16];
  float S0v[2], S1v[2];
  unsigned PARv[2];

#pragma unroll
  for (int r = 0; r < 2; ++r) {
    float g[16], sq0[16];
    int P0 = 0, P1 = 0;
    {
      const float4* xr4 = reinterpret_cast<const float4*>(x_in + (size_t)rows[r] * 16);
      float xv[16];
#pragma unroll
      for (int q = 0; q < 4; ++q) {
        float4 v = xr4[q];
        xv[q * 4 + 0] = v.x; xv[q * 4 + 1] = v.y;
        xv[q * 4 + 2] = v.z; xv[q * 4 + 3] = v.w;
      }
#pragma unroll
      for (int j = 0; j < 16; ++j) {
        float xj = xv[j] / a;
        float xhj = xj * 0.5f;                // exact
        xh[r][j] = xhj;
        float t0f = __builtin_rintf(xhj);
        float d0 = xhj - t0f;                 // exact
        float hm = xhj - 0.5f;
        float t1f = __builtin_rintf(hm);
        float d1 = hm - t1f;                  // exact
        P0 |= ((int)t0f & 1) << j;
        P1 |= ((int)t1f & 1) << j;
        sq0[j] = d0 * d0;
        g[tb.pt[j]] = __builtin_fmaf(d1, d1, -sq0[j]);  // delta by point
        T[r][tb.pt[j]] = __builtin_fabsf(d0);
        S[r][tb.pt[j]] = __builtin_fabsf(d1);
      }
    }
    S0v[r] = (((sq0[0] + sq0[1]) + (sq0[2] + sq0[3])) + ((sq0[4] + sq0[5]) + (sq0[6] + sq0[7])))
           + (((sq0[8] + sq0[9]) + (sq0[10] + sq0[11])) + ((sq0[12] + sq0[13]) + (sq0[14] + sq0[15])));

    // fast WHT on g (ssum path)
#pragma unroll
    for (int st = 1; st < 16; st <<= 1) {
#pragma unroll
      for (int p = 0; p < 16; ++p) {
        if (!(p & st)) {
          float u = g[p], v = g[p | st];
          g[p] = u + v;
          g[p | st] = u - v;
        }
      }
    }
    S1v[r] = S0v[r] + g[0];
    h[r][0] = 0.0f;
#pragma unroll
    for (int t = 1; t < 16; ++t) h[r][t] = 0.5f * (g[0] - g[t]);

    // butterfly max-DP: T[kap]=mx(2kap), S[kap]=mx(2kap+1)
#pragma unroll
    for (int st = 1; st < 16; st <<= 1) {
#pragma unroll
      for (int p = 0; p < 16; ++p) {
        if (!(p & st)) {
          float tA = T[r][p], tB = T[r][p | st];
          float sA = S[r][p], sB = S[r][p | st];
          T[r][p]      = __builtin_fmaxf(tA, tB);
          T[r][p | st] = __builtin_fmaxf(tA, sB);
          S[r][p]      = __builtin_fmaxf(sA, sB);
          S[r][p | st] = __builtin_fmaxf(sA, tB);
        }
      }
    }

    // PAR32: bit k = surrogate parity of candidate k
    unsigned Q = (unsigned)(P0 ^ P1);
    unsigned PAR = ((__builtin_popcount((unsigned)P0) & 1) ? 0xFFFFFFFFu : 0u) ^ tb.par2w;
    PAR ^= ((__builtin_popcount(Q & tb.rowm[0]) & 1) ? 0xFFFF0000u : 0u);
    PAR ^= ((__builtin_popcount(Q & tb.rowm[1]) & 1) ? 0xFF00FF00u : 0u);
    PAR ^= ((__builtin_popcount(Q & tb.rowm[2]) & 1) ? 0xF0F0F0F0u : 0u);
    PAR ^= ((__builtin_popcount(Q & tb.rowm[3]) & 1) ? 0xCCCCCCCCu : 0u);
    PAR ^= ((__builtin_popcount(Q & tb.rowm[4]) & 1) ? 0xAAAAAAAAu : 0u);
    PARv[r] = PAR;
  }

  // -------- pass 1: both rows interleaved per k (2 independent chains) ----
  float b1[2], b2[2], b3[2];
  int k1[2], k2[2], k3[2];
#pragma unroll
  for (int r = 0; r < 2; ++r) {
    b1[r] = __builtin_inff(); b2[r] = b1[r]; b3[r] = b1[r];
    k1[r] = 0; k2[r] = 0; k3[r] = 0;
  }

#pragma unroll
  for (int k = 0; k < 32; ++k) {
    const int kap = k >> 1;
#pragma unroll
    for (int r = 0; r < 2; ++r) {
      float s  = (k & 1) ? (S1v[r] - h[r][kap]) : (S0v[r] + h[r][kap]);
      float mx = (k & 1) ? S[r][kap] : T[r][kap];
      float spen = s + __builtin_fmaf(-2.0f, mx, 1.0f);
      float dtil = ((PARv[r] >> k) & 1u) ? spen : s;

      bool lt1 = dtil < b1[r], lt2 = dtil < b2[r], lt3 = dtil < b3[r];
      float nb3 = lt3 ? (lt2 ? b2[r] : dtil) : b3[r];  int nk3 = lt3 ? (lt2 ? k2[r] : k) : k3[r];
      float nb2 = lt2 ? (lt1 ? b1[r] : dtil) : b2[r];  int nk2 = lt2 ? (lt1 ? k1[r] : k) : k2[r];
      b3[r] = nb3; k3[r] = nk3;
      b2[r] = nb2; k2[r] = nk2;
      b1[r] = lt1 ? dtil : b1[r];  k1[r] = lt1 ? k : k1[r];
    }
  }

  // -------- pass 2 + emit per row (merged-emit, 3 evals) ------------------
#pragma unroll
  for (int r = 0; r < 2; ++r) {
    float yb[16], yt[16];
    float Db = eval_k(k1[r], xh[r], yb);
    int kb = k1[r];
    {
      float D2 = eval_k(k2[r], xh[r], yt);
      bool c2 = (D2 < Db) || (D2 == Db && k2[r] < kb);
      Db = c2 ? D2 : Db; kb = c2 ? k2[r] : kb;
#pragma unroll
      for (int j = 0; j < 16; ++j) yb[j] = c2 ? yt[j] : yb[j];
    }
    {
      float D3 = eval_k(k3[r], xh[r], yt);
      bool c3 = (D3 < Db) || (D3 == Db && k3[r] < kb);
#pragma unroll
      for (int j = 0; j < 16; ++j) yb[j] = c3 ? yt[j] : yb[j];
    }

    float4* yr4 = reinterpret_cast<float4*>(y_out + (size_t)rows[r] * 16);
#pragma unroll
    for (int q = 0; q < 4; ++q) {
      float4 v;
      v.x = yb[q * 4 + 0] * a; v.y = yb[q * 4 + 1] * a;
      v.z = yb[q * 4 + 2] * a; v.w = yb[q * 4 + 3] * a;
      yr4[q] = v;
    }
  }
}

extern "C" void kernel_launch(void* const* d_in, const int* in_sizes, int n_in,
                              void* d_out, int out_size, void* d_ws, size_t ws_size,
                              hipStream_t stream) {
  const float* x_in  = (const float*)d_in[0];
  const float* C_rep = (const float*)d_in[1];
  const float* a_ptr = (const float*)d_in[2];
  float* y_out = (float*)d_out;

  const int n_rows = in_sizes[0] / 16;
  const int half = n_rows >> 1;
  const int block = 256;
  const int grid = (half + block - 1) / block;
  bw_quant_kernel<<<grid, block, 0, stream>>>(x_in, C_rep, a_ptr, y_out, n_rows);
}

// Round 18
// 24.554 us; speedup vs baseline: 1.5186x; 1.5186x over previous
//
#include <hip/hip_runtime.h>

// Barnes-Wall Lambda16 quantizer — FINAL (R15 restored; session optimum).
// R2->R15: 69.8 -> 23.5 us (2.97x), absmax 0.0 throughout.
//
// Structure: one thread per row; surrogate pass-1 (WHT ssum + butterfly
// max-DP + PAR32 parity, fully unrolled, zero memory ops) ranks all 32
// cosets; bit-exact pass-2 (numpy-pipeline eval_k, LDS codebook rows)
// evaluates the top-3 with merged emit; lexicographic (D,k) = numpy
// first-min. launch_bounds(256,2): allocator targets ~128 VGPR (rule
// confirmed R3/R9/R13/R15: target ~ 256/N), grid caps occupancy at
// 4 waves/SIMD regardless, so the headroom is free.
//
// Why this is the ceiling (R16/R17 falsified the remaining hypotheses):
//  - memory ops / bank conflicts: R16 removed ALL LDS -> neutral.
//  - occupancy: R9/R13 (work-split) duplicate >, R17 (2 rows/thread ILP)
//    serialized -> all slower. Grid-capped 4 waves/SIMD stands.
//  - instruction count: R14-R16 cut ~30% -> ~2%. Latency-floor-bound.
//
// Pass-2 bit-exactness invariants (absmax 0.0):
//  - fp contract OFF; fmaf only where exact or single-rounding-identical:
//    fmaf(c,-0.5,xh) == fl(xh-c/2); fmaf(2,f,c) exact; Xp=fmaf(bit,+-2,X)
//    exact; e = fmaf(-2,xh,Xp) == fl(Xp-x) single rounding (x=2*xh exact).
//  - rintf == round-half-to-even == np.round; dd = x2 - f exact.
//  - first-max: contiguous-pair tournament, left wins ties (>=).
//  - parity (pass-2): float sum-tree of integer-valued f (exact), cvt, &1.
//  - D in numpy's n=16 pairwise order:
//    r[j]=sq[j]+sq[j+8]; D=((r0+r1)+(r2+r3))+((r4+r5)+(r6+r7)).

constexpr int G5[5][16] = {
    {1,1,1,1,0,1,0,1,1,0,0,1,0,0,0,0},
    {0,1,1,1,1,0,1,0,1,1,0,0,1,0,0,0},
    {0,0,1,1,1,1,0,1,0,1,1,0,0,1,0,0},
    {0,0,0,1,1,1,1,0,1,0,1,1,0,0,1,0},
    {1,1,1,1,1,1,1,1,1,1,1,1,1,1,1,1}};

struct Tabs {
  int m[16];        // column bit-masks: c_j(k) = popcount(k & m[j])
  int pt[16];       // pt[j] = 4-bit point (rows 0..3 at column j), bijective
  unsigned rowm[5]; // Row_i as bitmask over j
  unsigned par2w;   // bit k = par2(k) = XOR_j (c_j(k)>>1)&1
};
constexpr Tabs make_tabs() {
  Tabs t{};
  for (int j = 0; j < 16; ++j) {
    int m = 0;
    for (int i = 0; i < 5; ++i) m |= G5[i][j] << (4 - i);
    t.m[j] = m;
    t.pt[j] = (G5[0][j] << 3) | (G5[1][j] << 2) | (G5[2][j] << 1) | G5[3][j];
  }
  for (int i = 0; i < 5; ++i) {
    unsigned rm = 0;
    for (int j = 0; j < 16; ++j) rm |= (unsigned)G5[i][j] << j;
    t.rowm[i] = rm;
  }
  t.par2w = 0;
  for (int k = 0; k < 32; ++k) {
    unsigned p2 = 0;
    for (int j = 0; j < 16; ++j) {
      int c = 0;
      for (int i = 0; i < 5; ++i) c += ((k >> (4 - i)) & 1) * G5[i][j];
      p2 ^= (unsigned)((c >> 1) & 1);
    }
    t.par2w |= p2 << k;
  }
  return t;
}
constexpr Tabs tb = make_tabs();

__device__ __forceinline__ int parity16i(const float (&f)[16]) {
  // exact: all addends are small integers
  float s0 = ((f[0] + f[1]) + (f[2] + f[3])) + ((f[4] + f[5]) + (f[6] + f[7]));
  float s1 = ((f[8] + f[9]) + (f[10] + f[11])) + ((f[12] + f[13]) + (f[14] + f[15]));
  return ((int)(s0 + s1)) & 1;
}

// Exact numpy-pipeline evaluation of candidate kk (R2..R15-verified).
// Codeword row from LDS; always emits y (scaled candidate).
__device__ __forceinline__ float eval_k(int kk, const float (&xh)[16], float a,
                                        float (&y)[16], const float (*Cs)[16]) {
#pragma clang fp contract(off)
  float cf[16];
  {
    const float4* crow = reinterpret_cast<const float4*>(&Cs[kk][0]);
    float4 c0 = crow[0], c1 = crow[1], c2 = crow[2], c3 = crow[3];
    cf[0] = c0.x; cf[1] = c0.y; cf[2] = c0.z; cf[3] = c0.w;
    cf[4] = c1.x; cf[5] = c1.y; cf[6] = c1.z; cf[7] = c1.w;
    cf[8] = c2.x; cf[9] = c2.y; cf[10] = c2.z; cf[11] = c2.w;
    cf[12] = c3.x; cf[13] = c3.y; cf[14] = c3.z; cf[15] = c3.w;
  }
  float f[16], dd[16];
#pragma unroll
  for (int j = 0; j < 16; ++j) {
    float x2 = __builtin_fmaf(cf[j], -0.5f, xh[j]);  // == fl(xh - c/2)
    float fj = __builtin_rintf(x2);
    f[j] = fj;
    dd[j] = x2 - fj;                                 // exact
  }
  const int par = parity16i(f);

  // first-occurrence argmax of |dd| -> onehot (left wins ties)
  float tv[16];
  int ti[16];
#pragma unroll
  for (int j = 0; j < 16; ++j) { tv[j] = __builtin_fabsf(dd[j]); ti[j] = 1 << j; }
#pragma unroll
  for (int w = 8; w >= 1; w >>= 1) {
#pragma unroll
    for (int j = 0; j < w; ++j) {
      bool L = tv[2 * j] >= tv[2 * j + 1];
      tv[j] = L ? tv[2 * j] : tv[2 * j + 1];
      ti[j] = L ? ti[2 * j] : ti[2 * j + 1];
    }
  }
  const int ohm = par ? ti[0] : 0;   // patch mask (0 when parity even)

  float sq[16];
#pragma unroll
  for (int j = 0; j < 16; ++j) {
    float X  = __builtin_fmaf(2.0f, f[j], cf[j]);      // exact int
    float s2 = __builtin_copysignf(2.0f, dd[j]);       // corr direction
    float bitf = (float)((ohm >> j) & 1);
    float Xp = __builtin_fmaf(bitf, s2, X);            // exact int
    float e  = __builtin_fmaf(-2.0f, xh[j], Xp);       // == fl(Xp - x)
    sq[j] = e * e;
    y[j] = Xp * a;
  }
  float r0 = sq[0] + sq[8],  r1 = sq[1] + sq[9];
  float r2 = sq[2] + sq[10], r3 = sq[3] + sq[11];
  float r4 = sq[4] + sq[12], r5 = sq[5] + sq[13];
  float r6 = sq[6] + sq[14], r7 = sq[7] + sq[15];
  return ((r0 + r1) + (r2 + r3)) + ((r4 + r5) + (r6 + r7));
}

__global__ __launch_bounds__(256, 2) void bw_quant_kernel(
    const float* __restrict__ x_in,
    const float* __restrict__ C_rep,   // unused (constexpr codebook)
    const float* __restrict__ a_ptr,
    float* __restrict__ y_out,
    int n_rows)
{
#pragma clang fp contract(off)
  __shared__ alignas(16) float Cs[32][16];
  for (int i = threadIdx.x; i < 32 * 16; i += 256)
    Cs[i >> 4][i & 15] = (float)__builtin_popcount((i >> 4) & tb.m[i & 15]);
  __syncthreads();

  const int row = blockIdx.x * 256 + threadIdx.x;
  if (row >= n_rows) return;

  const float a = a_ptr[0];

  // -------- prologue: xh + residuals -> T/S/g/sq0 by point, parity masks --
  float xh[16], g[16], sq0[16], T[16], S[16];
  int P0 = 0, P1 = 0;
  {
    const float4* xr4 = reinterpret_cast<const float4*>(x_in + (size_t)row * 16);
    float xv[16];
#pragma unroll
    for (int q = 0; q < 4; ++q) {
      float4 v = xr4[q];
      xv[q * 4 + 0] = v.x; xv[q * 4 + 1] = v.y;
      xv[q * 4 + 2] = v.z; xv[q * 4 + 3] = v.w;
    }
#pragma unroll
    for (int j = 0; j < 16; ++j) {
      float xj = xv[j] / a;
      float xhj = xj * 0.5f;                // exact
      xh[j] = xhj;                          // live through both passes
      float t0 = __builtin_rintf(xhj);
      float d0 = xhj - t0;                  // exact
      float hm = xhj - 0.5f;
      float t1 = __builtin_rintf(hm);
      float d1 = hm - t1;                   // exact
      P0 |= ((int)t0 & 1) << j;
      P1 |= ((int)t1 & 1) << j;
      sq0[j] = d0 * d0;
      g[tb.pt[j]] = __builtin_fmaf(d1, d1, -sq0[j]);  // delta by point
      T[tb.pt[j]] = __builtin_fabsf(d0);              // u by point
      S[tb.pt[j]] = __builtin_fabsf(d1);              // w by point
    }
  }
  float S0 = (((sq0[0] + sq0[1]) + (sq0[2] + sq0[3])) + ((sq0[4] + sq0[5]) + (sq0[6] + sq0[7])))
           + (((sq0[8] + sq0[9]) + (sq0[10] + sq0[11])) + ((sq0[12] + sq0[13]) + (sq0[14] + sq0[15])));

  // fast WHT on g (ssum path, R11/R14/R15-validated)
#pragma unroll
  for (int st = 1; st < 16; st <<= 1) {
#pragma unroll
    for (int p = 0; p < 16; ++p) {
      if (!(p & st)) {
        float u = g[p], v = g[p | st];
        g[p] = u + v;
        g[p | st] = u - v;
      }
    }
  }
  float S1 = S0 + g[0];
  float h[16];
  h[0] = 0.0f;
#pragma unroll
  for (int t = 1; t < 16; ++t) h[t] = 0.5f * (g[0] - g[t]);

  // butterfly max-DP (R12/R14/R15-validated): T[kap]=mx(2kap), S[kap]=mx(2kap+1)
#pragma unroll
  for (int st = 1; st < 16; st <<= 1) {
#pragma unroll
    for (int p = 0; p < 16; ++p) {
      if (!(p & st)) {
        float tA = T[p], tB = T[p | st];
        float sA = S[p], sB = S[p | st];
        T[p]      = __builtin_fmaxf(tA, tB);
        T[p | st] = __builtin_fmaxf(tA, sB);
        S[p]      = __builtin_fmaxf(sA, sB);
        S[p | st] = __builtin_fmaxf(sA, tB);
      }
    }
  }

  // PAR32 (R12/R14/R15-validated): bit k = surrogate parity of candidate k
  unsigned PAR;
  {
    unsigned Q = (unsigned)(P0 ^ P1);
    PAR = ((__builtin_popcount((unsigned)P0) & 1) ? 0xFFFFFFFFu : 0u) ^ tb.par2w;
    PAR ^= ((__builtin_popcount(Q & tb.rowm[0]) & 1) ? 0xFFFF0000u : 0u);  // k bit 4
    PAR ^= ((__builtin_popcount(Q & tb.rowm[1]) & 1) ? 0xFF00FF00u : 0u);  // k bit 3
    PAR ^= ((__builtin_popcount(Q & tb.rowm[2]) & 1) ? 0xF0F0F0F0u : 0u);  // k bit 2
    PAR ^= ((__builtin_popcount(Q & tb.rowm[3]) & 1) ? 0xCCCCCCCCu : 0u);  // k bit 1
    PAR ^= ((__builtin_popcount(Q & tb.rowm[4]) & 1) ? 0xAAAAAAAAu : 0u);  // k bit 0
  }

  // -------- pass 1: fully unrolled surrogate ranking, stable top-3 --------
  float b1 = __builtin_inff(), b2 = b1, b3 = b1;
  int k1 = 0, k2 = 0, k3 = 0;

#pragma unroll
  for (int k = 0; k < 32; ++k) {
    const int kap = k >> 1;
    float s  = (k & 1) ? (S1 - h[kap]) : (S0 + h[kap]);   // WHT ssum
    float mx = (k & 1) ? S[kap] : T[kap];                 // DP max (register)
    float spen = s + __builtin_fmaf(-2.0f, mx, 1.0f);
    float dtil = ((PAR >> k) & 1u) ? spen : s;

    // stable top-3 insert (strict <: earlier k wins ties)
    bool lt1 = dtil < b1, lt2 = dtil < b2, lt3 = dtil < b3;
    float nb3 = lt3 ? (lt2 ? b2 : dtil) : b3;  int nk3 = lt3 ? (lt2 ? k2 : k) : k3;
    float nb2 = lt2 ? (lt1 ? b1 : dtil) : b2;  int nk2 = lt2 ? (lt1 ? k1 : k) : k2;
    b3 = nb3; k3 = nk3;
    b2 = nb2; k2 = nk2;
    b1 = lt1 ? dtil : b1;  k1 = lt1 ? k : k1;
  }

  // -------- pass 2: exact evals with running winner (merged emit) ---------
  float yb[16], yt[16];
  float Db = eval_k(k1, xh, a, yb, Cs);
  int kb = k1;
  {
    float D2 = eval_k(k2, xh, a, yt, Cs);
    bool c2 = (D2 < Db) || (D2 == Db && k2 < kb);
    Db = c2 ? D2 : Db; kb = c2 ? k2 : kb;
#pragma unroll
    for (int j = 0; j < 16; ++j) yb[j] = c2 ? yt[j] : yb[j];
  }
  {
    float D3 = eval_k(k3, xh, a, yt, Cs);
    bool c3 = (D3 < Db) || (D3 == Db && k3 < kb);
#pragma unroll
    for (int j = 0; j < 16; ++j) yb[j] = c3 ? yt[j] : yb[j];
  }

  float4* yr4 = reinterpret_cast<float4*>(y_out + (size_t)row * 16);
#pragma unroll
  for (int q = 0; q < 4; ++q) {
    float4 v;
    v.x = yb[q * 4 + 0]; v.y = yb[q * 4 + 1];
    v.z = yb[q * 4 + 2]; v.w = yb[q * 4 + 3];
    yr4[q] = v;
  }
}

extern "C" void kernel_launch(void* const* d_in, const int* in_sizes, int n_in,
                              void* d_out, int out_size, void* d_ws, size_t ws_size,
                              hipStream_t stream) {
  const float* x_in  = (const float*)d_in[0];
  const float* C_rep = (const float*)d_in[1];
  const float* a_ptr = (const float*)d_in[2];
  float* y_out = (float*)d_out;

  const int n_rows = in_sizes[0] / 16;
  const int block = 256;
  const int grid = (n_rows + block - 1) / block;
  bw_quant_kernel<<<grid, block, 0, stream>>>(x_in, C_rep, a_ptr, y_out, n_rows);
}